// Round 9
// baseline (358.423 us; speedup 1.0000x reference)
//
#include <hip/hip_runtime.h>

typedef _Float16 half2v __attribute__((ext_vector_type(2)));

namespace {
constexpr int Bn = 8, Cn = 256, Hn = 96, Wn = 128;
constexpr int HWn = Hn * Wn;          // 12288
constexpr int ND = 9;
constexpr int TH = 4, HQ = 24;        // 24 h-tiles of 4 rows
constexpr int NBLK = Bn * HQ * 2 * 2; // 768 = (b, ht, wh, chalf) -> exactly 3 blocks/CU
constexpr int PERX = NBLK / 8;        // 96 -> one batch image per XCD
// staged step (one channel-pair, fp16-pair u32s): s 12 rows x SP, f 4 rows x FP
constexpr int SP = 76;                // 72 cols (64 + 2x4 halo) + 4 pad, 16B-aligned rows
constexpr int FP = 68;                // 64 cols + 4 pad
constexpr int SSZ = 12 * SP;          // 912 u32
constexpr int STEP = SSZ + 4 * FP;    // 1184 u32 per step
constexpr int CHUNK = 2 * STEP;       // 2 steps per barrier
constexpr int NTASK = 560;            // 2 x (216 s + 64 f) staging tasks per chunk
}

__device__ __forceinline__ float dot2h(unsigned a, unsigned b, float c) {
#if __has_builtin(__builtin_amdgcn_fdot2)
  return __builtin_amdgcn_fdot2(__builtin_bit_cast(half2v, a),
                                __builtin_bit_cast(half2v, b), c, false);
#else
  float d;
  asm("v_dot2_f32_f16 %0, %1, %2, %3" : "=v"(d) : "v"(a), "v"(b), "v"(c));
  return d;
#endif
}

__device__ __forceinline__ unsigned pkh(float lo, float hi) {
  return __builtin_bit_cast(unsigned, __builtin_amdgcn_cvt_pkrtz(lo, hi));
}

__global__ __launch_bounds__(576, 6) void corr_fused(
    const float* __restrict__ first, const float* __restrict__ second,
    float* __restrict__ out)
{
  __shared__ __align__(16) unsigned LB[2][CHUNK];  // 18,944 B

  const int tid = threadIdx.x;
  const int dy = tid >> 6;          // wave = dy (0..8)
  const int lane = tid & 63;
  const int hs = lane >> 4;         // 0..3: row within tile
  const int w0 = (lane & 15) << 2;  // 4 px per lane (w-half local)

  const int bid = blockIdx.x;
  const int logical = (bid & 7) * PERX + (bid >> 3);  // XCD x -> batch image x
  const int b = logical / 96;
  int rest = logical % 96;
  const int ht = rest >> 2;
  const int wh = (rest >> 1) & 1;
  const int chalf = rest & 1;
  const int h0 = ht * TH;
  const int wb = wh * 64;
  const int cbase = chalf * 128;    // this block's 128 channels = 64 pairs

  // staging task decode (tid < 560): chunk = 2 steps; per step 216 s + 64 f tasks
  const int stp = tid / 280;        // step within chunk
  const int t2 = tid % 280;
  const bool isS = (t2 < 216);
  const int srow = t2 / 18, sq = t2 % 18;          // s: row 0..11, 16B-quad 0..17
  const int fr = (t2 - 216) >> 4, fq = (t2 - 216) & 15;  // f: row 0..3, quad 0..15
  const int sgrow = h0 - 4 + srow;
  const int sgcol = wb - 4 + 4 * sq;
  const bool svalid = (sgrow >= 0) & (sgrow < Hn) & (sgcol >= 0) & (sgcol <= 124);
  const int sgoff = ((b * Cn) * Hn + max(0, min(Hn - 1, sgrow))) * Wn +
                    max(0, min(124, sgcol));
  const int fgoff = ((b * Cn) * Hn + (h0 + fr)) * Wn + wb + 4 * fq;
  const int ldst = stp * STEP + (isS ? (srow * SP + 4 * sq) : (SSZ + fr * FP + 4 * fq));

  float acc[ND][4];
#pragma unroll
  for (int dx = 0; dx < ND; ++dx)
#pragma unroll
    for (int p = 0; p < 4; ++p) acc[dx][p] = 0.f;

  float4 ga, gb;   // staged loads in flight (2 channels of one float4-quad)
  auto LOADS = [&](int k) {     // issue global loads for chunk k
    if (tid < NTASK) {
      const int c0 = cbase + 4 * k + 2 * stp;   // pair p = 2k+stp -> channels c0,c0+1
      if (isS) {
        ga = make_float4(0.f, 0.f, 0.f, 0.f);
        gb = ga;
        if (svalid) {
          const float* p0 = second + c0 * HWn + sgoff;
          ga = *(const float4*)(p0);
          gb = *(const float4*)(p0 + HWn);
        }
      } else {
        const float* p0 = first + c0 * HWn + fgoff;
        ga = *(const float4*)(p0);
        gb = *(const float4*)(p0 + HWn);
      }
    }
  };
  auto WRITES = [&](unsigned* lb) {  // pack fp16 pairs, write 16B to LDS
    if (tid < NTASK) {
      uint4 u;
      u.x = pkh(ga.x, gb.x); u.y = pkh(ga.y, gb.y);
      u.z = pkh(ga.z, gb.z); u.w = pkh(ga.w, gb.w);
      *(uint4*)(lb + ldst) = u;
    }
  };

  auto COMPUTE = [&](const unsigned* lb) {
#pragma unroll
    for (int s = 0; s < 2; ++s) {
      const unsigned* base = lb + s * STEP;
      const unsigned* sp = base + (hs + dy) * SP + w0;  // staged col idx = local col + 4
      uint4 s0 = *(const uint4*)(sp);
      uint4 s1 = *(const uint4*)(sp + 4);
      uint4 s2 = *(const uint4*)(sp + 8);
      uint4 fx = *(const uint4*)(base + SSZ + hs * FP + w0);
      const unsigned sw[12] = {s0.x, s0.y, s0.z, s0.w, s1.x, s1.y,
                               s1.z, s1.w, s2.x, s2.y, s2.z, s2.w};
      const unsigned fv[4] = {fx.x, fx.y, fx.z, fx.w};
#pragma unroll
      for (int dx = 0; dx < ND; ++dx)
#pragma unroll
        for (int p = 0; p < 4; ++p)
          acc[dx][p] = dot2h(fv[p], sw[p + dx], acc[dx][p]);
    }
  };

  LOADS(0);
  WRITES(&LB[0][0]);
  __syncthreads();
#pragma unroll 1
  for (int k = 0; k < 32; ++k) {     // 32 chunks x 2 pair-steps = 128 channels
    if (k < 31) LOADS(k + 1);
    COMPUTE(&LB[k & 1][0]);
    if (k < 31) WRITES(&LB[(k + 1) & 1][0]);
    __syncthreads();
  }

  // epilogue: fp32 atomic accumulate (2 chalf contributors, commutative -> deterministic)
  const float sc = 1.0f / Cn;
  float* ob = out + ((size_t)(b * 81 + dy * ND) * Hn + (h0 + hs)) * Wn + wb + w0;
#pragma unroll
  for (int dx = 0; dx < ND; ++dx) {
    float* q = ob + (size_t)dx * HWn;
#pragma unroll
    for (int p = 0; p < 4; ++p)
      unsafeAtomicAdd(q + p, acc[dx][p] * sc);
  }
}

extern "C" void kernel_launch(void* const* d_in, const int* in_sizes, int n_in,
                              void* d_out, int out_size, void* d_ws, size_t ws_size,
                              hipStream_t stream) {
  const float* first = (const float*)d_in[0];
  const float* second = (const float*)d_in[1];
  float* out = (float*)d_out;
  hipMemsetAsync(out, 0, (size_t)out_size * sizeof(float), stream);
  corr_fused<<<dim3(NBLK), dim3(576), 0, stream>>>(first, second, out);
}

// Round 10
// 144.943 us; speedup vs baseline: 2.4729x; 2.4729x over previous
//
#include <hip/hip_runtime.h>

typedef _Float16 half2v __attribute__((ext_vector_type(2)));

namespace {
constexpr int Bn = 8, Cn = 256, Hn = 96, Wn = 128;
constexpr int HWn = Hn * Wn;          // 12288
constexpr int ND = 9;
constexpr int TH = 4, HQ = 24;        // 24 h-tiles of 4 rows
constexpr int NBLK = Bn * HQ;         // 192 blocks, 9 waves each
constexpr int PERX = NBLK / 8;        // 24 -> one batch image per XCD
constexpr int ROWP = 132;             // LDS row pitch (u32) - R8-measured conflict-free
constexpr int STEPSZ = 16 * ROWP;     // 12 s-rows + 4 f-rows per pair-step
}

__device__ __forceinline__ unsigned dpp_shr1(unsigned x) {  // lane i <- i-1 (16-row local)
  return (unsigned)__builtin_amdgcn_update_dpp(0, (int)x, 0x111, 0xF, 0xF, true);
}
__device__ __forceinline__ unsigned dpp_shl1(unsigned x) {  // lane i <- i+1
  return (unsigned)__builtin_amdgcn_update_dpp(0, (int)x, 0x101, 0xF, 0xF, true);
}

__device__ __forceinline__ float dot2h(unsigned a, unsigned b, float c) {
#if __has_builtin(__builtin_amdgcn_fdot2)
  return __builtin_amdgcn_fdot2(__builtin_bit_cast(half2v, a),
                                __builtin_bit_cast(half2v, b), c, false);
#else
  float d;
  asm("v_dot2_f32_f16 %0, %1, %2, %3" : "=v"(d) : "v"(a), "v"(b), "v"(c));
  return d;
#endif
}

__device__ __forceinline__ unsigned pkh(float lo, float hi) {
  return __builtin_bit_cast(unsigned, __builtin_amdgcn_cvt_pkrtz(lo, hi));
}

__global__ __launch_bounds__(576, 1) void corr_fused(
    const float* __restrict__ first, const float* __restrict__ second,
    float* __restrict__ out)
{
  __shared__ __align__(16) unsigned LB[2][2 * STEPSZ];  // 33,792 B (R8-identical)

  const int tid = threadIdx.x;
  const int dy = tid >> 6;          // wave = dy (0..8)
  const int lane = tid & 63;
  const int hs = (lane >> 4) & 3;   // h-row within tile (16-lane group = image row)
  const int w0 = (lane & 15) << 3;  // 8 px per lane, full 128-w row

  const int bid = blockIdx.x;
  const int logical = (bid & 7) * PERX + (bid >> 3);  // XCD x -> batch image x
  const int b = logical / HQ;
  const int h0 = (logical % HQ) * TH;

  // staging tasks: chunk = 2 pair-steps; per step 16 rows x 32 quads = 512 tasks.
  // 1024 tasks over 576 threads -> t0 always, t1 for tid<448.
  const int t0 = tid, t1 = tid + 576;

  float acc[ND][8];
#pragma unroll
  for (int dx = 0; dx < ND; ++dx)
#pragma unroll
    for (int p = 0; p < 8; ++p) acc[dx][p] = 0.f;

  float4 ga0, gb0, ga1, gb1;  // in-flight fp32 loads (channel pair per task)
  auto LOADT = [&](int t, int k, float4& ga, float4& gb) {
    const int step = t >> 9;          // pair-step within chunk
    const int r = (t >> 5) & 15;      // staged row (0..11 = s, 12..15 = f)
    const int li = t & 31;            // 16B quad column
    const int c0 = 4 * k + 2 * step;  // channel pair -> channels c0, c0+1
    if (r < 12) {
      const int grow = h0 - 4 + r;
      if (grow >= 0 && grow < Hn) {
        const float* p0 = second + ((size_t)(b * Cn + c0) * Hn + grow) * Wn + li * 4;
        ga = *(const float4*)(p0);
        gb = *(const float4*)(p0 + HWn);
      } else {
        ga = make_float4(0.f, 0.f, 0.f, 0.f);
        gb = ga;
      }
    } else {
      const float* p0 = first + ((size_t)(b * Cn + c0) * Hn + (h0 + r - 12)) * Wn + li * 4;
      ga = *(const float4*)(p0);
      gb = *(const float4*)(p0 + HWn);
    }
  };
  auto LOADS = [&](int k) {
    LOADT(t0, k, ga0, gb0);
    if (t1 < 1024) LOADT(t1, k, ga1, gb1);
  };
  auto WRITET = [&](int t, unsigned* lb, const float4& ga, const float4& gb) {
    const int step = t >> 9;
    const int r = (t >> 5) & 15;
    const int li = t & 31;
    uint4 u;
    u.x = pkh(ga.x, gb.x); u.y = pkh(ga.y, gb.y);
    u.z = pkh(ga.z, gb.z); u.w = pkh(ga.w, gb.w);
    *(uint4*)(lb + step * STEPSZ + r * ROWP + li * 4) = u;
  };
  auto WRITES = [&](unsigned* lb) {
    WRITET(t0, lb, ga0, gb0);
    if (t1 < 1024) WRITET(t1, lb, ga1, gb1);
  };

  auto COMPUTE = [&](const unsigned* lb) {   // R8-identical
#pragma unroll
    for (int s = 0; s < 2; ++s) {
      const unsigned* base = lb + s * STEPSZ;
      const unsigned* srow = base + (hs + dy) * ROWP + w0;
      const unsigned* frow = base + (12 + hs) * ROWP + w0;
      uint4 sA = *(const uint4*)(srow);
      uint4 sB = *(const uint4*)(srow + 4);
      uint4 fA = *(const uint4*)(frow);
      uint4 fB = *(const uint4*)(frow + 4);
      const unsigned o0 = sA.x, o1 = sA.y, o2 = sA.z, o3 = sA.w;
      const unsigned o4 = sB.x, o5 = sB.y, o6 = sB.z, o7 = sB.w;
      const unsigned sw[16] = {
          dpp_shr1(o4), dpp_shr1(o5), dpp_shr1(o6), dpp_shr1(o7),
          o0, o1, o2, o3, o4, o5, o6, o7,
          dpp_shl1(o0), dpp_shl1(o1), dpp_shl1(o2), dpp_shl1(o3)};
      const unsigned fv[8] = {fA.x, fA.y, fA.z, fA.w, fB.x, fB.y, fB.z, fB.w};
#pragma unroll
      for (int dx = 0; dx < ND; ++dx)
#pragma unroll
        for (int p = 0; p < 8; ++p)
          acc[dx][p] = dot2h(fv[p], sw[p + dx], acc[dx][p]);
    }
  };

  // write-early depth-2 pipeline:
  //   iter k: [barrier] WRITE(k+1: loads landed ~1 full iter ago) ->
  //           issue LOADS(k+2) -> COMPUTE(k) -> [barrier]
  LOADS(0);
  WRITES(&LB[0][0]);
  LOADS(1);
  __syncthreads();
#pragma unroll 1
  for (int k = 0; k < 64; ++k) {     // 64 chunks x 2 pair-steps = 256 channels
    if (k < 63) WRITES(&LB[(k + 1) & 1][0]);
    if (k < 62) LOADS(k + 2);
    COMPUTE(&LB[k & 1][0]);
    __syncthreads();
  }

  // epilogue: direct coalesced stores (no atomics)
  const float sc = 1.0f / Cn;
  float* obase = out + ((size_t)(b * 81 + dy * ND) * Hn + (h0 + hs)) * Wn + w0;
#pragma unroll
  for (int dx = 0; dx < ND; ++dx) {
    float4 q0 = make_float4(acc[dx][0] * sc, acc[dx][1] * sc,
                            acc[dx][2] * sc, acc[dx][3] * sc);
    float4 q1 = make_float4(acc[dx][4] * sc, acc[dx][5] * sc,
                            acc[dx][6] * sc, acc[dx][7] * sc);
    *(float4*)(obase + (size_t)dx * HWn) = q0;
    *(float4*)(obase + (size_t)dx * HWn + 4) = q1;
  }
}

extern "C" void kernel_launch(void* const* d_in, const int* in_sizes, int n_in,
                              void* d_out, int out_size, void* d_ws, size_t ws_size,
                              hipStream_t stream) {
  const float* first = (const float*)d_in[0];
  const float* second = (const float*)d_in[1];
  float* out = (float*)d_out;
  corr_fused<<<dim3(NBLK), dim3(576), 0, stream>>>(first, second, out);
}